// Round 10
// baseline (123.862 us; speedup 1.0000x reference)
//
#include <hip/hip_runtime.h>
#include <math.h>

#define B_ 1024
#define D_ 2048
#define M_ 32
#define H_ 32

#define DPB 16        // d per block
#define DPW 4         // d per wave, sequential (wave-uniform d -> SGPR weights)
#define CB  64        // b per block = lanes per wave
#define OPAD 17       // out-gather pad

// Abramowitz & Stegun 7.1.26, |err| <= 1.5e-7 absolute. Uses hw rcp + exp.
__device__ __forceinline__ float fast_erff(float x) {
    float ax = fabsf(x);
    float t  = __builtin_amdgcn_rcpf(1.0f + 0.3275911f * ax);
    float p  = 1.061405429f;
    p = p * t - 1.453152027f;
    p = p * t + 1.421413741f;
    p = p * t - 0.284496736f;
    p = p * t + 0.254829592f;
    float e = __expf(-ax * ax);
    float r = 1.0f - p * t * e;
    return copysignf(r, x);
}

__device__ __forceinline__ float gelu_exact(float x) {
    return 0.5f * x * (1.0f + fast_erff(x * 0.70710678118f));
}

// tanh(x) = 1 - 2/(exp(2x)+1); exp(inf)->inf->rcp->0 gives +/-1 at extremes.
__device__ __forceinline__ float fast_tanhf(float x) {
    return 1.0f - 2.0f * __builtin_amdgcn_rcpf(__expf(2.0f * x) + 1.0f);
}

__global__ __launch_bounds__(256)   // NO min-waves hint: hint causes load-sinking (r7/r8)
void nlm_kernel(const float* __restrict__ pre,
                const float* __restrict__ w1,
                const float* __restrict__ b1,
                const float* __restrict__ w_out,
                const float* __restrict__ b_out,
                float* __restrict__ out) {
    __shared__ float obuf[CB * OPAD];   // 4.35 KB

    const int tid  = threadIdx.x;
    const int lane = tid & 63;
    const int w    = tid >> 6;                  // 0..3
    const int bx   = blockIdx.x;
    const int dt   = bx & (D_ / DPB - 1);       // 0..127: consecutive blocks walk d
    const int bt   = bx >> 7;                   // 0..15
    const int d0   = dt * DPB;
    const int b0   = bt * CB;
    const int b    = b0 + lane;

    // Wave-uniform d base -> SGPR weight addressing (s_load path).
    const int du = __builtin_amdgcn_readfirstlane(d0 + w * DPW);
    const float* __restrict__ prow = pre + ((size_t)b * D_ + du) * M_;

#pragma unroll 1
    for (int i = 0; i < DPW; ++i) {
        const int dd = du + i;
        const float* __restrict__ wr  = w1    + (size_t)dd * (H_ * M_);
        const float* __restrict__ b1r = b1    + (size_t)dd * H_;
        const float* __restrict__ wor = w_out + (size_t)dd * H_;

        // ---- load pre row (8 float4), then PIN (r9-proven anti-remat) ----
        float4 rv[8];
#pragma unroll
        for (int mg = 0; mg < 8; ++mg)
            rv[mg] = *reinterpret_cast<const float4*>(prow + i * M_ + mg * 4);
#pragma unroll
        for (int mg = 0; mg < 8; ++mg)
            asm volatile("" : "+v"(rv[mg].x), "+v"(rv[mg].y),
                              "+v"(rv[mg].z), "+v"(rv[mg].w));

        // ---- h-outer: weights read CONTIGUOUSLY (128 B per h), prefetchable ----
        float s = 0.f;
#pragma unroll 2
        for (int h = 0; h < H_; ++h) {
            float xe = b1r[h], xo = 0.f;
#pragma unroll
            for (int mg = 0; mg < 8; ++mg) {
                xe = fmaf(rv[mg].x, wr[h * M_ + mg * 4 + 0], xe);
                xo = fmaf(rv[mg].y, wr[h * M_ + mg * 4 + 1], xo);
                xe = fmaf(rv[mg].z, wr[h * M_ + mg * 4 + 2], xe);
                xo = fmaf(rv[mg].w, wr[h * M_ + mg * 4 + 3], xo);
            }
            s = fmaf(gelu_exact(xe + xo), wor[h], s);
        }

        obuf[lane * OPAD + (w * DPW + i)] = fast_tanhf(s + b_out[dd]);
    }

    __syncthreads();

    // ---- flush: thread t -> row r=t>>2, 16-B chunk c=(t&3)*4; dwordx4 stores ----
    {
        const int r = tid >> 2;
        const int c = (tid & 3) * 4;
        float4 o;
        o.x = obuf[r * OPAD + c + 0];
        o.y = obuf[r * OPAD + c + 1];
        o.z = obuf[r * OPAD + c + 2];
        o.w = obuf[r * OPAD + c + 3];
        *reinterpret_cast<float4*>(out + (size_t)(b0 + r) * D_ + d0 + c) = o;
    }
}

extern "C" void kernel_launch(void* const* d_in, const int* in_sizes, int n_in,
                              void* d_out, int out_size, void* d_ws, size_t ws_size,
                              hipStream_t stream) {
    const float* pre   = (const float*)d_in[0];
    const float* w1    = (const float*)d_in[1];
    const float* b1    = (const float*)d_in[2];
    const float* w_out = (const float*)d_in[3];
    const float* b_out = (const float*)d_in[4];
    float* out = (float*)d_out;

    const int grid = (D_ / DPB) * (B_ / CB);   // 128 * 16 = 2048
    nlm_kernel<<<dim3(grid), dim3(256), 0, stream>>>(pre, w1, b1, w_out, b_out, out);
}

// Round 11
// 97.847 us; speedup vs baseline: 1.2659x; 1.2659x over previous
//
#include <hip/hip_runtime.h>
#include <math.h>

#define B_ 1024
#define D_ 2048
#define M_ 32
#define H_ 32

#define DPB 8         // d per block = 8 waves, ONE d per wave (r4's proven amortization)
#define BPB 128       // b per block; lane owns 2 consecutive b-rows (r4 verbatim)
#define OPAD 9        // out-gather row pad (stride 9 floats -> 2-way banks, free)

// Abramowitz & Stegun 7.1.26, |err| <= 1.5e-7 absolute. Uses hw rcp + exp.
__device__ __forceinline__ float fast_erff(float x) {
    float ax = fabsf(x);
    float t  = __builtin_amdgcn_rcpf(1.0f + 0.3275911f * ax);
    float p  = 1.061405429f;
    p = p * t - 1.453152027f;
    p = p * t + 1.421413741f;
    p = p * t - 0.284496736f;
    p = p * t + 0.254829592f;
    float e = __expf(-ax * ax);
    float r = 1.0f - p * t * e;
    return copysignf(r, x);
}

__device__ __forceinline__ float gelu_exact(float x) {
    return 0.5f * x * (1.0f + fast_erff(x * 0.70710678118f));
}

// tanh(x) = 1 - 2/(exp(2x)+1); exp(inf)->inf->rcp->0 gives +/-1 at extremes.
__device__ __forceinline__ float fast_tanhf(float x) {
    return 1.0f - 2.0f * __builtin_amdgcn_rcpf(__expf(2.0f * x) + 1.0f);
}

__global__ __launch_bounds__(512)
void nlm_kernel(const float* __restrict__ pre,
                const float* __restrict__ w1,
                const float* __restrict__ b1,
                const float* __restrict__ w_out,
                const float* __restrict__ b_out,
                float* __restrict__ out) {
    __shared__ float obuf[BPB * OPAD];   // 4.6 KB

    const int tid  = threadIdx.x;
    const int lane = tid & 63;
    const int w    = tid >> 6;              // 0..7: wave -> one d

    // XCD-aware swizzle: hardware round-robins blockIdx across the 8 XCDs, so
    // remap to give each XCD a CONTIGUOUS run of 256 logical blocks. The 4
    // dt-neighbors sharing each 128-B out line then hit the same XCD L2 ->
    // partial-line writebacks merge before HBM; pre reads gain L2 locality.
    const int linear = ((blockIdx.x & 7) << 8) | (blockIdx.x >> 3);   // bijective (2048 = 8*256)
    const int dt = linear & 255;            // 0..255, consecutive within an XCD
    const int bt = linear >> 8;             // 0..7
    const int d0 = dt * DPB;
    const int b0 = bt * BPB;

    // Wave-uniform d -> SGPR weight addressing (s_load path), r4-proven.
    const int du = __builtin_amdgcn_readfirstlane(d0 + w);
    const float* __restrict__ wr  = w1    + (size_t)du * (H_ * M_);
    const float* __restrict__ b1r = b1    + (size_t)du * H_;
    const float* __restrict__ wor = w_out + (size_t)du * H_;
    const float  bo = b_out[du];

    // ---- per-lane pre rows -> scalar arrays at function top (r4 verbatim:
    // nothing to sink into; this form measured resident & fast) ----
    const int b = b0 + lane * 2;
    const float* row0 = pre + ((size_t)b * D_ + du) * M_;
    const float* row1 = row0 + (size_t)D_ * M_;
    float a0[M_], a1[M_];
#pragma unroll
    for (int mg = 0; mg < M_ / 4; ++mg) {
        const float4 v0 = *reinterpret_cast<const float4*>(row0 + mg * 4);
        const float4 v1 = *reinterpret_cast<const float4*>(row1 + mg * 4);
        a0[mg * 4 + 0] = v0.x; a0[mg * 4 + 1] = v0.y; a0[mg * 4 + 2] = v0.z; a0[mg * 4 + 3] = v0.w;
        a1[mg * 4 + 0] = v1.x; a1[mg * 4 + 1] = v1.y; a1[mg * 4 + 2] = v1.z; a1[mg * 4 + 3] = v1.w;
    }

    // ---- h-outer loop; w operands from SGPRs (r4 verbatim) ----
    float s0 = 0.f, s1 = 0.f;
#pragma unroll 2
    for (int h = 0; h < H_; ++h) {
        float x0 = b1r[h];
        float x1 = x0;
#pragma unroll
        for (int m = 0; m < M_; ++m) {
            const float wv = wr[h * M_ + m];
            x0 = fmaf(a0[m], wv, x0);
            x1 = fmaf(a1[m], wv, x1);
        }
        const float wo = wor[h];
        s0 += gelu_exact(x0) * wo;
        s1 += gelu_exact(x1) * wo;
    }

    obuf[(lane * 2 + 0) * OPAD + w] = fast_tanhf(s0 + bo);
    obuf[(lane * 2 + 1) * OPAD + w] = fast_tanhf(s1 + bo);

    __syncthreads();

    // ---- flush: 256 threads store one float4 each; 32 B contiguous per
    // b-row pair, all 8 d of this block's tile -> minimal line splitting ----
    if (tid < 2 * BPB) {
        const int r = tid >> 1;             // 0..127
        const int c = (tid & 1) * 4;        // 0 or 4
        float4 o;
        o.x = obuf[r * OPAD + c + 0];
        o.y = obuf[r * OPAD + c + 1];
        o.z = obuf[r * OPAD + c + 2];
        o.w = obuf[r * OPAD + c + 3];
        *reinterpret_cast<float4*>(out + (size_t)(b0 + r) * D_ + d0 + c) = o;
    }
}

extern "C" void kernel_launch(void* const* d_in, const int* in_sizes, int n_in,
                              void* d_out, int out_size, void* d_ws, size_t ws_size,
                              hipStream_t stream) {
    const float* pre   = (const float*)d_in[0];
    const float* w1    = (const float*)d_in[1];
    const float* b1    = (const float*)d_in[2];
    const float* w_out = (const float*)d_in[3];
    const float* b_out = (const float*)d_in[4];
    float* out = (float*)d_out;

    const int grid = (D_ / DPB) * (B_ / BPB);   // 256 * 8 = 2048
    nlm_kernel<<<dim3(grid), dim3(512), 0, stream>>>(pre, w1, b1, w_out, b_out, out);
}

// Round 12
// 58.236 us; speedup vs baseline: 2.1269x; 1.6802x over previous
//
#include <hip/hip_runtime.h>
#include <math.h>

#define B_ 1024
#define D_ 2048
#define M_ 32
#define H_ 32

#define DPB 8         // d per block = 8 waves, one d per wave
#define BPB 128       // b per block = 8 b-tiles of 16 rows
#define OPAD 9        // out-gather row pad

typedef _Float16 f16x8 __attribute__((ext_vector_type(8)));
typedef float    f32x4 __attribute__((ext_vector_type(4)));

// Abramowitz & Stegun 7.1.26, |err| <= 1.5e-7 absolute. Uses hw rcp + exp.
__device__ __forceinline__ float fast_erff(float x) {
    float ax = fabsf(x);
    float t  = __builtin_amdgcn_rcpf(1.0f + 0.3275911f * ax);
    float p  = 1.061405429f;
    p = p * t - 1.453152027f;
    p = p * t + 1.421413741f;
    p = p * t - 0.284496736f;
    p = p * t + 0.254829592f;
    float e = __expf(-ax * ax);
    float r = 1.0f - p * t * e;
    return copysignf(r, x);
}

__device__ __forceinline__ float gelu_exact(float x) {
    return 0.5f * x * (1.0f + fast_erff(x * 0.70710678118f));
}

// tanh(x) = 1 - 2/(exp(2x)+1); exp(inf)->inf->rcp->0 gives +/-1 at extremes.
__device__ __forceinline__ float fast_tanhf(float x) {
    return 1.0f - 2.0f * __builtin_amdgcn_rcpf(__expf(2.0f * x) + 1.0f);
}

__device__ __forceinline__ f16x8 cvt8(const float4 a, const float4 b) {
    f16x8 v;
    v[0] = (_Float16)a.x; v[1] = (_Float16)a.y; v[2] = (_Float16)a.z; v[3] = (_Float16)a.w;
    v[4] = (_Float16)b.x; v[5] = (_Float16)b.y; v[6] = (_Float16)b.z; v[7] = (_Float16)b.w;
    return v;
}

__global__ __launch_bounds__(512)
void nlm_kernel(const float* __restrict__ pre,
                const float* __restrict__ w1,
                const float* __restrict__ b1,
                const float* __restrict__ w_out,
                const float* __restrict__ b_out,
                float* __restrict__ out) {
    __shared__ float obuf[BPB * OPAD];   // 4.6 KB

    const int tid  = threadIdx.x;
    const int lane = tid & 63;
    const int w    = tid >> 6;          // 0..7: wave -> one d
    const int c16  = lane & 15;         // A-row h / B-col b / C-col b
    const int g    = lane >> 4;         // 0..3: k-group (k = g*8 + j)

    // XCD-aware bijective swizzle (r11): contiguous runs per XCD.
    const int linear = ((blockIdx.x & 7) << 8) | (blockIdx.x >> 3);
    const int dt = linear & 255;
    const int bt = linear >> 8;
    const int d0 = dt * DPB;
    const int b0 = bt * BPB;

    const int du = __builtin_amdgcn_readfirstlane(d0 + w);

    // ---- A operand: W[h = c16 (+16 for tile1)][k = g*8 + j], contiguous 32 B ----
    const float* wbase = w1 + (size_t)du * (H_ * M_);
    const f16x8 wa0 = cvt8(*(const float4*)(wbase + c16 * M_ + g * 8),
                           *(const float4*)(wbase + c16 * M_ + g * 8 + 4));
    const f16x8 wa1 = cvt8(*(const float4*)(wbase + (c16 + 16) * M_ + g * 8),
                           *(const float4*)(wbase + (c16 + 16) * M_ + g * 8 + 4));

    // ---- per-lane bias / w_out quads for C-rows h = g*4 + r (and +16) ----
    const f32x4 b1q0 = *(const f32x4*)(b1    + (size_t)du * H_ + g * 4);
    const f32x4 b1q1 = *(const f32x4*)(b1    + (size_t)du * H_ + g * 4 + 16);
    const f32x4 woq0 = *(const f32x4*)(w_out + (size_t)du * H_ + g * 4);
    const f32x4 woq1 = *(const f32x4*)(w_out + (size_t)du * H_ + g * 4 + 16);
    const float bo   = b_out[du];

    // B operand base: P[k = g*8+j][b = b0 + t*16 + c16] = pre[b][du][k]
    const float* pbase = pre + ((size_t)(b0 + c16) * D_ + du) * M_ + g * 8;

#pragma unroll 2
    for (int t = 0; t < 8; ++t) {
        const float* pa = pbase + (size_t)t * 16 * D_ * M_;
        const f16x8 pf = cvt8(*(const float4*)(pa), *(const float4*)(pa + 4));

        // C[h][b] += W[h][k] * P[k][b]; accs initialized with b1 (free bias add)
        f32x4 acc0 = b1q0, acc1 = b1q1;
        acc0 = __builtin_amdgcn_mfma_f32_16x16x32_f16(wa0, pf, acc0, 0, 0, 0);
        acc1 = __builtin_amdgcn_mfma_f32_16x16x32_f16(wa1, pf, acc1, 0, 0, 0);

        // ---- second layer: per-lane partial over its 8 h, then 2-step reduce ----
        float p = 0.f;
#pragma unroll
        for (int r = 0; r < 4; ++r) {
            p = fmaf(gelu_exact(acc0[r]), woq0[r], p);
            p = fmaf(gelu_exact(acc1[r]), woq1[r], p);
        }
        p += __shfl_xor(p, 16, 64);
        p += __shfl_xor(p, 32, 64);

        if (lane < 16)
            obuf[(t * 16 + c16) * OPAD + w] = fast_tanhf(p + bo);
    }

    __syncthreads();

    // ---- flush: 256 threads store one float4; full-line-friendly (r11-proven) ----
    if (tid < 2 * BPB) {
        const int r  = tid >> 1;            // 0..127
        const int cc = (tid & 1) * 4;       // 0 or 4
        float4 o;
        o.x = obuf[r * OPAD + cc + 0];
        o.y = obuf[r * OPAD + cc + 1];
        o.z = obuf[r * OPAD + cc + 2];
        o.w = obuf[r * OPAD + cc + 3];
        *reinterpret_cast<float4*>(out + (size_t)(b0 + r) * D_ + d0 + cc) = o;
    }
}

extern "C" void kernel_launch(void* const* d_in, const int* in_sizes, int n_in,
                              void* d_out, int out_size, void* d_ws, size_t ws_size,
                              hipStream_t stream) {
    const float* pre   = (const float*)d_in[0];
    const float* w1    = (const float*)d_in[1];
    const float* b1    = (const float*)d_in[2];
    const float* w_out = (const float*)d_in[3];
    const float* b_out = (const float*)d_in[4];
    float* out = (float*)d_out;

    const int grid = (D_ / DPB) * (B_ / BPB);   // 256 * 8 = 2048
    nlm_kernel<<<dim3(grid), dim3(512), 0, stream>>>(pre, w1, b1, w_out, b_out, out);
}

// Round 14
// 56.904 us; speedup vs baseline: 2.1767x; 1.0234x over previous
//
#include <hip/hip_runtime.h>
#include <math.h>

#define B_ 1024
#define D_ 2048
#define M_ 32
#define H_ 32

#define DPB 8         // d per block = 8 waves, one d per wave
#define BPB 128       // b per block = 8 b-tiles of 16 rows
#define OPAD 9        // out-gather row pad

typedef _Float16 f16x8 __attribute__((ext_vector_type(8)));
typedef __fp16   h16x2 __attribute__((ext_vector_type(2)));
typedef __fp16   h16x4 __attribute__((ext_vector_type(4)));
typedef __fp16   h16x8 __attribute__((ext_vector_type(8)));
typedef float    f32x4 __attribute__((ext_vector_type(4)));

// Abramowitz & Stegun 7.1.26, |err| <= 1.5e-7 absolute. Uses hw rcp + exp.
__device__ __forceinline__ float fast_erff(float x) {
    float ax = fabsf(x);
    float t  = __builtin_amdgcn_rcpf(1.0f + 0.3275911f * ax);
    float p  = 1.061405429f;
    p = p * t - 1.453152027f;
    p = p * t + 1.421413741f;
    p = p * t - 0.284496736f;
    p = p * t + 0.254829592f;
    float e = __expf(-ax * ax);
    float r = 1.0f - p * t * e;
    return copysignf(r, x);
}

__device__ __forceinline__ float gelu_exact(float x) {
    return 0.5f * x * (1.0f + fast_erff(x * 0.70710678118f));
}

// tanh(x) = 1 - 2/(exp(2x)+1); exp(inf)->inf->rcp->0 gives +/-1 at extremes.
__device__ __forceinline__ float fast_tanhf(float x) {
    return 1.0f - 2.0f * __builtin_amdgcn_rcpf(__expf(2.0f * x) + 1.0f);
}

// Packed fp32->fp16 (RTZ): 4 v_cvt_pkrtz instead of 8 scalar cvts.
__device__ __forceinline__ f16x8 cvt8(const float4 a, const float4 b) {
    const h16x2 h0 = __builtin_amdgcn_cvt_pkrtz(a.x, a.y);
    const h16x2 h1 = __builtin_amdgcn_cvt_pkrtz(a.z, a.w);
    const h16x2 h2 = __builtin_amdgcn_cvt_pkrtz(b.x, b.y);
    const h16x2 h3 = __builtin_amdgcn_cvt_pkrtz(b.z, b.w);
    const h16x4 lo = __builtin_shufflevector(h0, h1, 0, 1, 2, 3);
    const h16x4 hi = __builtin_shufflevector(h2, h3, 0, 1, 2, 3);
    const h16x8 v  = __builtin_shufflevector(lo, hi, 0, 1, 2, 3, 4, 5, 6, 7);
    return __builtin_bit_cast(f16x8, v);
}

// Load b-tile T's B-fragment halves (2 x float4, 32 B per lane, contiguous).
#define LOADT(T, RA, RB)                                                       \
    {                                                                          \
        const float* pa_ = pbase + (size_t)(T) * 16 * D_ * M_;                 \
        RA = *reinterpret_cast<const float4*>(pa_);                            \
        RB = *reinterpret_cast<const float4*>(pa_ + 4);                        \
    }

// Process b-tile T from registers RA/RB (r12-proven body).
#define PROCT(T, RA, RB)                                                       \
    {                                                                          \
        const f16x8 pf = cvt8(RA, RB);                                         \
        f32x4 acc0 = b1q0, acc1 = b1q1;                                        \
        acc0 = __builtin_amdgcn_mfma_f32_16x16x32_f16(wa0, pf, acc0, 0, 0, 0); \
        acc1 = __builtin_amdgcn_mfma_f32_16x16x32_f16(wa1, pf, acc1, 0, 0, 0); \
        float p = 0.f;                                                         \
        _Pragma("unroll")                                                      \
        for (int r = 0; r < 4; ++r) {                                          \
            p = fmaf(gelu_exact(acc0[r]), woq0[r], p);                         \
            p = fmaf(gelu_exact(acc1[r]), woq1[r], p);                         \
        }                                                                      \
        p += __shfl_xor(p, 16, 64);                                            \
        p += __shfl_xor(p, 32, 64);                                            \
        if (lane < 16)                                                         \
            obuf[((T) * 16 + c16) * OPAD + w] = fast_tanhf(p + bo);            \
    }

__global__ __launch_bounds__(512)
void nlm_kernel(const float* __restrict__ pre,
                const float* __restrict__ w1,
                const float* __restrict__ b1,
                const float* __restrict__ w_out,
                const float* __restrict__ b_out,
                float* __restrict__ out) {
    __shared__ float obuf[BPB * OPAD];   // 4.6 KB

    const int tid  = threadIdx.x;
    const int lane = tid & 63;
    const int w    = tid >> 6;          // 0..7: wave -> one d
    const int c16  = lane & 15;         // A-row h / B-col b
    const int g    = lane >> 4;         // 0..3: k-group (k = g*8 + j)

    // XCD-aware bijective swizzle (r11): contiguous runs per XCD.
    const int linear = ((blockIdx.x & 7) << 8) | (blockIdx.x >> 3);
    const int dt = linear & 255;
    const int bt = linear >> 8;
    const int d0 = dt * DPB;
    const int b0 = bt * BPB;

    const int du = __builtin_amdgcn_readfirstlane(d0 + w);

    // ---- A operand: W[h = c16 (+16)][k = g*8 + j], contiguous 32 B ----
    const float* wbase = w1 + (size_t)du * (H_ * M_);
    const f16x8 wa0 = cvt8(*(const float4*)(wbase + c16 * M_ + g * 8),
                           *(const float4*)(wbase + c16 * M_ + g * 8 + 4));
    const f16x8 wa1 = cvt8(*(const float4*)(wbase + (c16 + 16) * M_ + g * 8),
                           *(const float4*)(wbase + (c16 + 16) * M_ + g * 8 + 4));

    // ---- per-lane bias / w_out quads for C-rows h = g*4 + r (and +16) ----
    const f32x4 b1q0 = *(const f32x4*)(b1    + (size_t)du * H_ + g * 4);
    const f32x4 b1q1 = *(const f32x4*)(b1    + (size_t)du * H_ + g * 4 + 16);
    const f32x4 woq0 = *(const f32x4*)(w_out + (size_t)du * H_ + g * 4);
    const f32x4 woq1 = *(const f32x4*)(w_out + (size_t)du * H_ + g * 4 + 16);
    const float bo   = b_out[du];

    // B operand base: P[k = g*8+j][b = b0 + t*16 + c16] = pre[b][du][k]
    const float* pbase = pre + ((size_t)(b0 + c16) * D_ + du) * M_ + g * 8;

    // ---- depth-2 software pipeline: every load in flight across 2 epilogues ----
    float4 xA, xB, yA, yB;
    LOADT(0, xA, xB)
    LOADT(1, yA, yB)
    PROCT(0, xA, xB)  LOADT(2, xA, xB)
    PROCT(1, yA, yB)  LOADT(3, yA, yB)
    PROCT(2, xA, xB)  LOADT(4, xA, xB)
    PROCT(3, yA, yB)  LOADT(5, yA, yB)
    PROCT(4, xA, xB)  LOADT(6, xA, xB)
    PROCT(5, yA, yB)  LOADT(7, yA, yB)
    PROCT(6, xA, xB)
    PROCT(7, yA, yB)

    __syncthreads();

    // ---- flush: 256 threads store one float4; full-line-friendly (r11-proven) ----
    if (tid < 2 * BPB) {
        const int r  = tid >> 1;            // 0..127
        const int cc = (tid & 1) * 4;       // 0 or 4
        float4 o;
        o.x = obuf[r * OPAD + cc + 0];
        o.y = obuf[r * OPAD + cc + 1];
        o.z = obuf[r * OPAD + cc + 2];
        o.w = obuf[r * OPAD + cc + 3];
        *reinterpret_cast<float4*>(out + (size_t)(b0 + r) * D_ + d0 + cc) = o;
    }
}

extern "C" void kernel_launch(void* const* d_in, const int* in_sizes, int n_in,
                              void* d_out, int out_size, void* d_ws, size_t ws_size,
                              hipStream_t stream) {
    const float* pre   = (const float*)d_in[0];
    const float* w1    = (const float*)d_in[1];
    const float* b1    = (const float*)d_in[2];
    const float* w_out = (const float*)d_in[3];
    const float* b_out = (const float*)d_in[4];
    float* out = (float*)d_out;

    const int grid = (D_ / DPB) * (B_ / BPB);   // 256 * 8 = 2048
    nlm_kernel<<<dim3(grid), dim3(512), 0, stream>>>(pre, w1, b1, w_out, b_out, out);
}